// Round 1
// baseline (287.990 us; speedup 1.0000x reference)
//
#include <hip/hip_runtime.h>

typedef __attribute__((ext_vector_type(8))) short short8;
typedef __attribute__((ext_vector_type(4))) float f32x4;

#define XP_ELEMS (32u * 66u * 66u * 128u)  /* 17,842,176 bf16 elements */
#define WT_ELEMS (256u * 1152u)            /* 294,912 bf16 elements */
#define WS_NEED  ((size_t)(XP_ELEMS + WT_ELEMS) * 2u)

typedef const __attribute__((address_space(1))) void* gp1_t;
typedef __attribute__((address_space(3))) void* lp3_t;

__device__ __forceinline__ void gload16(const void* g, void* l) {
  __builtin_amdgcn_global_load_lds((gp1_t)g, (lp3_t)l, 16, 0, 0);
}

__device__ __forceinline__ short f2bf(float f) {
  unsigned u = __float_as_uint(f);
  u = (u + 0x7FFFu + ((u >> 16) & 1u)) >> 16;  // RNE truncate to bf16
  return (short)u;
}

// x[b][cin][h][w] fp32  ->  x_p[b][h+1][w+1][cin] bf16, zero halo of 1.
__global__ __launch_bounds__(256) void prepass_x(const float* __restrict__ x,
                                                 short* __restrict__ xp) {
  int tid  = blockIdx.x * 256 + threadIdx.x;
  int o8   = tid * 8;           // 8 contiguous cin per thread
  int cin0 = o8 & 127;
  int pix  = o8 >> 7;
  int px   = pix % 66;
  int t2   = pix / 66;
  int py   = t2 % 66;
  int b    = t2 / 66;
  short8 v;
  if (px == 0 || px == 65 || py == 0 || py == 65) {
    v = (short8)0;
  } else {
    const float* src = x + (((long)(b * 128 + cin0) * 64 + (py - 1)) * 64 + (px - 1));
#pragma unroll
    for (int i = 0; i < 8; ++i) v[i] = f2bf(src[(long)i * 4096]);
  }
  *(short8*)(xp + o8) = v;
}

// weight[cout][cin][kh][kw] fp32 -> w_t[cout][kh][kw][cin] bf16 (k=(kh*3+kw)*128+cin)
__global__ __launch_bounds__(256) void prepass_w(const float* __restrict__ w,
                                                 short* __restrict__ wt) {
  int o    = blockIdx.x * 256 + threadIdx.x;  // < 294912 exactly
  int cout = o / 1152;
  int r    = o % 1152;
  int kh   = r / 384;
  int kw   = (r / 128) % 3;
  int cin  = r & 127;
  wt[o] = f2bf(w[((cout * 128 + cin) * 3 + kh) * 3 + kw]);
}

// Implicit-GEMM conv: C[m=cout][n=b*4096+y*64+x], 128x128 tile, BK=32,
// 4 waves x (64x64 = 4x4 of 16x16x32 bf16 MFMA). m97-style 2-barrier K-loop
// with global_load_lds width-16 staging. LDS rows: 32 bf16 = 64 B (no pad:
// required for lane-contiguous global_load_lds dests; bank-uniform for b128).
__global__ __launch_bounds__(256) void conv_gemm(const short* __restrict__ xp,
                                                 const short* __restrict__ wt,
                                                 float* __restrict__ out) {
  __shared__ short Alds[128 * 32];
  __shared__ short Blds[128 * 32];
  const int tid   = threadIdx.x;
  const int w     = tid >> 6;   // wave id 0..3 (uniform per wave)
  const int l     = tid & 63;
  const int l15   = l & 15;
  const int q     = l >> 4;
  const int ntile = blockIdx.x; // 0..1023
  const int m0    = blockIdx.y << 7;  // 0 or 128

  // staging mapping: lane covers row = c*64 + w*16 + (l>>2), k-chunk (l&3)*8
  const int srow = (w << 4) + (l >> 2);
  const int sch8 = (l & 3) * 8;

  const long aoff0 = (long)(m0 + srow) * 1152 + sch8;
  const long aoff1 = aoff0 + (long)64 * 1152;

  long boff[2];
#pragma unroll
  for (int c = 0; c < 2; ++c) {
    int ng = (ntile << 7) + (c << 6) + srow;  // global n; tile never spans images
    int b = ng >> 12, yx = ng & 4095;
    int y = yx >> 6, xx = yx & 63;
    // base pixel (y, xx) in padded coords; (kh,kw) shift added per step
    boff[c] = ((long)(b * 66 + y) * 66 + xx) * 128 + sch8;
  }

  short* Adst0 = &Alds[(w << 4) * 32];
  short* Adst1 = Adst0 + 64 * 32;
  short* Bdst0 = &Blds[(w << 4) * 32];
  short* Bdst1 = Bdst0 + 64 * 32;

  f32x4 acc[4][4];
#pragma unroll
  for (int i = 0; i < 4; ++i)
#pragma unroll
    for (int j = 0; j < 4; ++j) acc[i][j] = (f32x4)0.f;

  const int wm = (w >> 1) << 6;  // wave's 64-row offset in tile
  const int wn = (w & 1) << 6;   // wave's 64-col offset in tile

#pragma unroll
  for (int khkw = 0; khkw < 9; ++khkw) {
    const int kh = khkw / 3, kw = khkw % 3;
    const long sB = (long)(kh * 66 + kw) * 128;  // uniform shift into x_p
    const int kkb = khkw << 7;
#pragma unroll
    for (int c4 = 0; c4 < 4; ++c4) {
      const int cin0 = c4 << 5;
      const int kk0  = kkb + cin0;
      gload16(wt + aoff0 + kk0, Adst0);
      gload16(wt + aoff1 + kk0, Adst1);
      gload16(xp + boff[0] + sB + cin0, Bdst0);
      gload16(xp + boff[1] + sB + cin0, Bdst1);
      __syncthreads();  // drains vmcnt -> staged data visible
      short8 af[4], bf[4];
#pragma unroll
      for (int i = 0; i < 4; ++i)
        af[i] = *(const short8*)&Alds[(wm + (i << 4) + l15) * 32 + q * 8];
#pragma unroll
      for (int j = 0; j < 4; ++j)
        bf[j] = *(const short8*)&Blds[(wn + (j << 4) + l15) * 32 + q * 8];
#pragma unroll
      for (int i = 0; i < 4; ++i)
#pragma unroll
        for (int j = 0; j < 4; ++j)
          acc[i][j] = __builtin_amdgcn_mfma_f32_16x16x32_bf16(af[i], bf[j],
                                                              acc[i][j], 0, 0, 0);
      __syncthreads();  // protect LDS before next stage overwrites
    }
  }

  // epilogue: C/D layout col=lane&15, row=quad*4+reg (m89/m91-verified)
  const int ngb = (ntile << 7) + wn;
  const int b   = ngb >> 12;
  const int yxb = ngb & 4095;
  float* outb = out + (long)b * (256 * 4096) + yxb + l15;
#pragma unroll
  for (int i = 0; i < 4; ++i) {
#pragma unroll
    for (int r = 0; r < 4; ++r) {
      const int cout = m0 + wm + (i << 4) + q * 4 + r;
      float* orow = outb + (long)cout * 4096;
#pragma unroll
      for (int j = 0; j < 4; ++j) orow[j * 16] = acc[i][j][r];
    }
  }
}

// Correctness fallback if workspace is too small (slow, fp32 direct conv).
__global__ __launch_bounds__(256) void naive_conv(const float* __restrict__ x,
                                                  const float* __restrict__ wgt,
                                                  float* __restrict__ out) {
  long o = (long)blockIdx.x * 256 + threadIdx.x;
  int xx = (int)(o & 63);
  int y  = (int)((o >> 6) & 63);
  int co = (int)((o >> 12) & 255);
  int b  = (int)(o >> 20);
  float s = 0.f;
  for (int ci = 0; ci < 128; ++ci) {
    for (int kh = 0; kh < 3; ++kh) {
      int iy = y + kh - 1;
      if (iy < 0 || iy > 63) continue;
      for (int kw = 0; kw < 3; ++kw) {
        int ix = xx + kw - 1;
        if (ix < 0 || ix > 63) continue;
        s += x[((long)(b * 128 + ci) * 64 + iy) * 64 + ix] *
             wgt[((co * 128 + ci) * 3 + kh) * 3 + kw];
      }
    }
  }
  out[o] = s;
}

extern "C" void kernel_launch(void* const* d_in, const int* in_sizes, int n_in,
                              void* d_out, int out_size, void* d_ws, size_t ws_size,
                              hipStream_t stream) {
  (void)in_sizes; (void)n_in;
  const float* x   = (const float*)d_in[0];
  const float* wgt = (const float*)d_in[1];
  float* out = (float*)d_out;
  if (ws_size >= WS_NEED) {
    short* xp = (short*)d_ws;
    short* wt = xp + XP_ELEMS;
    prepass_x<<<dim3(XP_ELEMS / (256 * 8)), dim3(256), 0, stream>>>(x, xp);
    prepass_w<<<dim3(WT_ELEMS / 256), dim3(256), 0, stream>>>(wgt, wt);
    conv_gemm<<<dim3(1024, 2), dim3(256), 0, stream>>>(xp, wt, out);
  } else {
    naive_conv<<<dim3(out_size / 256), dim3(256), 0, stream>>>(x, wgt, out);
  }
}

// Round 2
// 274.275 us; speedup vs baseline: 1.0500x; 1.0500x over previous
//
#include <hip/hip_runtime.h>

typedef __attribute__((ext_vector_type(8))) short short8;
typedef __attribute__((ext_vector_type(4))) float f32x4;

#define XP_ELEMS (32u * 66u * 66u * 128u)  /* 17,842,176 bf16 elements */
#define WT_ELEMS (256u * 1152u)            /* 294,912 bf16 elements */
#define WS_NEED  ((size_t)(XP_ELEMS + WT_ELEMS) * 2u)

typedef const __attribute__((address_space(1))) void* gp1_t;
typedef __attribute__((address_space(3))) void* lp3_t;

__device__ __forceinline__ void gload16(const void* g, void* l) {
  __builtin_amdgcn_global_load_lds((gp1_t)g, (lp3_t)l, 16, 0, 0);
}

__device__ __forceinline__ short f2bf(float f) {
  unsigned u = __float_as_uint(f);
  u = (u + 0x7FFFu + ((u >> 16) & 1u)) >> 16;  // RNE truncate to bf16
  return (short)u;
}

// Transpose one (b, y) plane: x[b][cin][y][px] fp32 -> x_p[b][y+1][px+1][cin] bf16.
// Coalesced float4 reads, LDS round-trip (granule XOR swizzle: 2-way max = free),
// coalesced short8 writes. Halo (px=0/65 cols; py=0/65 rows) zeroed here too.
__global__ __launch_bounds__(256) void prepass_x(const float* __restrict__ x,
                                                 short* __restrict__ xp) {
  __shared__ short lds[64 * 128];  // [px][cin, granule-swizzled], 16 KB
  const int y = blockIdx.x;   // 0..63
  const int b = blockIdx.y;   // 0..31
  const int t = threadIdx.x;

  const float* src = x + (long)b * 128 * 4096 + y * 64;
#pragma unroll
  for (int i = 0; i < 8; ++i) {
    int f4 = t + i * 256;          // 0..2047
    int cin = f4 >> 4, px4 = f4 & 15;
    float4 v = *(const float4*)(src + (long)cin * 4096 + px4 * 4);
    float vv[4] = {v.x, v.y, v.z, v.w};
#pragma unroll
    for (int j = 0; j < 4; ++j) {
      int px = px4 * 4 + j;
      int g = (cin >> 3) ^ ((px ^ (px >> 2)) & 15);
      lds[px * 128 + (g << 3) + (cin & 7)] = f2bf(vv[j]);
    }
  }
  __syncthreads();
  short* dst = xp + ((long)(b * 66 + y + 1) * 66 + 1) * 128;
#pragma unroll
  for (int i = 0; i < 4; ++i) {
    int f8 = t + i * 256;          // 0..1023
    int px = f8 >> 4, c8 = f8 & 15;
    int g = c8 ^ ((px ^ (px >> 2)) & 15);
    short8 v = *(const short8*)&lds[px * 128 + (g << 3)];
    *(short8*)(dst + (long)px * 128 + c8 * 8) = v;
  }
  // column halo px=0 / px=65 for this padded row
  short8 z = (short8)0;
  short* rowbase = xp + (long)(b * 66 + y + 1) * 66 * 128;
  if (t < 32) {
    int px = (t < 16) ? 0 : 65;
    int c8 = t & 15;
    *(short8*)(rowbase + (long)px * 128 + c8 * 8) = z;
  }
  if (y == 0) {
    short* r0 = xp + (long)(b * 66) * 66 * 128;
    for (int idx = t; idx < 66 * 16; idx += 256) *(short8*)(r0 + idx * 8) = z;
  }
  if (y == 63) {
    short* r65 = xp + ((long)(b * 66) + 65) * 66 * 128;
    for (int idx = t; idx < 66 * 16; idx += 256) *(short8*)(r65 + idx * 8) = z;
  }
}

// weight[cout][cin][kh][kw] fp32 -> w_t[cout][kh][kw][cin] bf16 (k=(kh*3+kw)*128+cin)
__global__ __launch_bounds__(256) void prepass_w(const float* __restrict__ w,
                                                 short* __restrict__ wt) {
  int o    = blockIdx.x * 256 + threadIdx.x;  // < 294912 exactly
  int cout = o / 1152;
  int r    = o % 1152;
  int kh   = r / 384;
  int kw   = (r / 128) % 3;
  int cin  = r & 127;
  wt[o] = f2bf(w[((cout * 128 + cin) * 3 + kh) * 3 + kw]);
}

// Implicit-GEMM conv: C[m=cout][n=b*4096+y*64+x], 128x128 tile, BK=32,
// 4 waves x (64x64 = 4x4 of 16x16x32 bf16 MFMA), global_load_lds width-16.
// k-chunk XOR swizzle ((row>>1)&3) makes ds_read_b128 frag reads conflict-free
// while keeping global_load_lds destinations lane-linear.
__global__ __launch_bounds__(256) void conv_gemm(const short* __restrict__ xp,
                                                 const short* __restrict__ wt,
                                                 float* __restrict__ out) {
  __shared__ short Alds[128 * 32];
  __shared__ short Blds[128 * 32];
  const int tid   = threadIdx.x;
  const int w     = tid >> 6;   // wave id 0..3 (uniform per wave)
  const int l     = tid & 63;
  const int l15   = l & 15;
  const int q     = l >> 4;
  const int ntile = blockIdx.x; // 0..1023
  const int m0    = blockIdx.y << 7;  // 0 or 128

  // staging: lane covers row = w*16 + (l>>2); LDS granule pos l&3 holds
  // source k-chunk (l&3)^swz(row)  (swz self-inverse)
  const int srow = (w << 4) + (l >> 2);
  const int sch8 = (((l & 3) ^ ((srow >> 1) & 3)) * 8);

  const long aoff0 = (long)(m0 + srow) * 1152 + sch8;
  const long aoff1 = aoff0 + (long)64 * 1152;

  long boff[2];
#pragma unroll
  for (int c = 0; c < 2; ++c) {
    int ng = (ntile << 7) + (c << 6) + srow;  // global n; tile never spans images
    int b = ng >> 12, yx = ng & 4095;
    int y = yx >> 6, xx = yx & 63;
    boff[c] = ((long)(b * 66 + y) * 66 + xx) * 128 + sch8;
  }

  short* Adst0 = &Alds[(w << 4) * 32];
  short* Adst1 = Adst0 + 64 * 32;
  short* Bdst0 = &Blds[(w << 4) * 32];
  short* Bdst1 = Bdst0 + 64 * 32;

  f32x4 acc[4][4];
#pragma unroll
  for (int i = 0; i < 4; ++i)
#pragma unroll
    for (int j = 0; j < 4; ++j) acc[i][j] = (f32x4)0.f;

  const int wm = (w >> 1) << 6;  // wave's 64-row offset in tile
  const int wn = (w & 1) << 6;   // wave's 64-col offset in tile

#pragma unroll
  for (int khkw = 0; khkw < 9; ++khkw) {
    const int kh = khkw / 3, kw = khkw % 3;
    const long sB = (long)(kh * 66 + kw) * 128;  // uniform shift into x_p
    const int kkb = khkw << 7;
#pragma unroll
    for (int c4 = 0; c4 < 4; ++c4) {
      const int cin0 = c4 << 5;
      const int kk0  = kkb + cin0;
      gload16(wt + aoff0 + kk0, Adst0);
      gload16(wt + aoff1 + kk0, Adst1);
      gload16(xp + boff[0] + sB + cin0, Bdst0);
      gload16(xp + boff[1] + sB + cin0, Bdst1);
      __syncthreads();  // drains vmcnt -> staged data visible
      short8 af[4], bf[4];
#pragma unroll
      for (int i = 0; i < 4; ++i) {
        int rA = wm + (i << 4) + l15;
        af[i] = *(const short8*)&Alds[rA * 32 + ((q ^ ((rA >> 1) & 3)) << 3)];
      }
#pragma unroll
      for (int j = 0; j < 4; ++j) {
        int rB = wn + (j << 4) + l15;
        bf[j] = *(const short8*)&Blds[rB * 32 + ((q ^ ((rB >> 1) & 3)) << 3)];
      }
#pragma unroll
      for (int i = 0; i < 4; ++i)
#pragma unroll
        for (int j = 0; j < 4; ++j)
          acc[i][j] = __builtin_amdgcn_mfma_f32_16x16x32_bf16(af[i], bf[j],
                                                              acc[i][j], 0, 0, 0);
      __syncthreads();  // protect LDS before next stage overwrites
    }
  }

  // epilogue: C/D layout col=lane&15, row=quad*4+reg (m89/m91-verified)
  const int ngb = (ntile << 7) + wn;
  const int b   = ngb >> 12;
  const int yxb = ngb & 4095;
  float* outb = out + (long)b * (256 * 4096) + yxb + l15;
#pragma unroll
  for (int i = 0; i < 4; ++i) {
#pragma unroll
    for (int r = 0; r < 4; ++r) {
      const int cout = m0 + wm + (i << 4) + q * 4 + r;
      float* orow = outb + (long)cout * 4096;
#pragma unroll
      for (int j = 0; j < 4; ++j) orow[j * 16] = acc[i][j][r];
    }
  }
}

// Correctness fallback if workspace is too small (slow, fp32 direct conv).
__global__ __launch_bounds__(256) void naive_conv(const float* __restrict__ x,
                                                  const float* __restrict__ wgt,
                                                  float* __restrict__ out) {
  long o = (long)blockIdx.x * 256 + threadIdx.x;
  int xx = (int)(o & 63);
  int y  = (int)((o >> 6) & 63);
  int co = (int)((o >> 12) & 255);
  int b  = (int)(o >> 20);
  float s = 0.f;
  for (int ci = 0; ci < 128; ++ci) {
    for (int kh = 0; kh < 3; ++kh) {
      int iy = y + kh - 1;
      if (iy < 0 || iy > 63) continue;
      for (int kw = 0; kw < 3; ++kw) {
        int ix = xx + kw - 1;
        if (ix < 0 || ix > 63) continue;
        s += x[((long)(b * 128 + ci) * 64 + iy) * 64 + ix] *
             wgt[((co * 128 + ci) * 3 + kh) * 3 + kw];
      }
    }
  }
  out[o] = s;
}

extern "C" void kernel_launch(void* const* d_in, const int* in_sizes, int n_in,
                              void* d_out, int out_size, void* d_ws, size_t ws_size,
                              hipStream_t stream) {
  (void)in_sizes; (void)n_in;
  const float* x   = (const float*)d_in[0];
  const float* wgt = (const float*)d_in[1];
  float* out = (float*)d_out;
  if (ws_size >= WS_NEED) {
    short* xp = (short*)d_ws;
    short* wt = xp + XP_ELEMS;
    prepass_x<<<dim3(64, 32), dim3(256), 0, stream>>>(x, xp);
    prepass_w<<<dim3(WT_ELEMS / 256), dim3(256), 0, stream>>>(wgt, wt);
    conv_gemm<<<dim3(1024, 2), dim3(256), 0, stream>>>(xp, wt, out);
  } else {
    naive_conv<<<dim3(out_size / 256), dim3(256), 0, stream>>>(x, wgt, out);
  }
}

// Round 3
// 265.657 us; speedup vs baseline: 1.0841x; 1.0324x over previous
//
#include <hip/hip_runtime.h>

typedef __attribute__((ext_vector_type(8))) short short8;
typedef __attribute__((ext_vector_type(4))) float f32x4;

#define XP_ELEMS (32u * 66u * 66u * 128u)  /* 17,842,176 bf16 elements */
#define WT_ELEMS (256u * 1152u)            /* 294,912 bf16 elements */
#define WS_NEED  ((size_t)(XP_ELEMS + WT_ELEMS) * 2u)

typedef const __attribute__((address_space(1))) void* gp1_t;
typedef __attribute__((address_space(3))) void* lp3_t;

__device__ __forceinline__ void gload16(const void* g, void* l) {
  __builtin_amdgcn_global_load_lds((gp1_t)g, (lp3_t)l, 16, 0, 0);
}

__device__ __forceinline__ short f2bf(float f) {
  unsigned u = __float_as_uint(f);
  u = (u + 0x7FFFu + ((u >> 16) & 1u)) >> 16;  // RNE truncate to bf16
  return (short)u;
}

// Transpose one (b, y) plane: x[b][cin][y][px] fp32 -> x_p[b][y+1][px+1][cin] bf16.
// Coalesced float4 reads, LDS round-trip (granule XOR swizzle), coalesced short8
// writes. Halo (px=0/65 cols; py=0/65 rows) zeroed here too.
__global__ __launch_bounds__(256) void prepass_x(const float* __restrict__ x,
                                                 short* __restrict__ xp) {
  __shared__ short lds[64 * 128];  // [px][cin, granule-swizzled], 16 KB
  const int y = blockIdx.x;   // 0..63
  const int b = blockIdx.y;   // 0..31
  const int t = threadIdx.x;

  const float* src = x + (long)b * 128 * 4096 + y * 64;
#pragma unroll
  for (int i = 0; i < 8; ++i) {
    int f4 = t + i * 256;          // 0..2047
    int cin = f4 >> 4, px4 = f4 & 15;
    float4 v = *(const float4*)(src + (long)cin * 4096 + px4 * 4);
    float vv[4] = {v.x, v.y, v.z, v.w};
#pragma unroll
    for (int j = 0; j < 4; ++j) {
      int px = px4 * 4 + j;
      int g = (cin >> 3) ^ ((px ^ (px >> 2)) & 15);
      lds[px * 128 + (g << 3) + (cin & 7)] = f2bf(vv[j]);
    }
  }
  __syncthreads();
  short* dst = xp + ((long)(b * 66 + y + 1) * 66 + 1) * 128;
#pragma unroll
  for (int i = 0; i < 4; ++i) {
    int f8 = t + i * 256;          // 0..1023
    int px = f8 >> 4, c8 = f8 & 15;
    int g = c8 ^ ((px ^ (px >> 2)) & 15);
    short8 v = *(const short8*)&lds[px * 128 + (g << 3)];
    *(short8*)(dst + (long)px * 128 + c8 * 8) = v;
  }
  // column halo px=0 / px=65 for this padded row
  short8 z = (short8)0;
  short* rowbase = xp + (long)(b * 66 + y + 1) * 66 * 128;
  if (t < 32) {
    int px = (t < 16) ? 0 : 65;
    int c8 = t & 15;
    *(short8*)(rowbase + (long)px * 128 + c8 * 8) = z;
  }
  if (y == 0) {
    short* r0 = xp + (long)(b * 66) * 66 * 128;
    for (int idx = t; idx < 66 * 16; idx += 256) *(short8*)(r0 + idx * 8) = z;
  }
  if (y == 63) {
    short* r65 = xp + ((long)(b * 66) + 65) * 66 * 128;
    for (int idx = t; idx < 66 * 16; idx += 256) *(short8*)(r65 + idx * 8) = z;
  }
}

// weight[cout][cin][kh][kw] fp32 -> w_t[cout][kh][kw][cin] bf16 (k=(kh*3+kw)*128+cin)
__global__ __launch_bounds__(256) void prepass_w(const float* __restrict__ w,
                                                 short* __restrict__ wt) {
  int o    = blockIdx.x * 256 + threadIdx.x;  // < 294912 exactly
  int cout = o / 1152;
  int r    = o % 1152;
  int kh   = r / 384;
  int kw   = (r / 128) % 3;
  int cin  = r & 127;
  wt[o] = f2bf(w[((cout * 128 + cin) * 3 + kh) * 3 + kw]);
}

// Implicit-GEMM conv: C[m=cout][n=b*4096+y*64+x], 128x128 tile, BK=64
// (2x 32-k chunks per barrier pair -> 18 pairs instead of 36), 4 waves x
// (64x64 = 4x4 of 16x16x32 bf16 MFMA), global_load_lds width-16.
// k-chunk XOR swizzle ((row>>1)&3) keeps ds_read_b128 frag reads conflict-free
// while keeping global_load_lds destinations lane-linear.
__global__ __launch_bounds__(256) void conv_gemm(const short* __restrict__ xp,
                                                 const short* __restrict__ wt,
                                                 float* __restrict__ out) {
  __shared__ short Alds[2 * 128 * 32];  // [chunk][row][32k]
  __shared__ short Blds[2 * 128 * 32];
  const int tid   = threadIdx.x;
  const int w     = tid >> 6;   // wave id 0..3 (uniform per wave)
  const int l     = tid & 63;
  const int l15   = l & 15;
  const int q     = l >> 4;
  const int ntile = blockIdx.x; // 0..1023
  const int m0    = blockIdx.y << 7;  // 0 or 128

  // staging: lane covers row = w*16 + (l>>2); LDS granule pos l&3 holds
  // source k-chunk (l&3)^swz(row)  (swz self-inverse)
  const int srow = (w << 4) + (l >> 2);
  const int sch8 = (((l & 3) ^ ((srow >> 1) & 3)) * 8);

  const long aoff0 = (long)(m0 + srow) * 1152 + sch8;
  const long aoff1 = aoff0 + (long)64 * 1152;

  long boff[2];
#pragma unroll
  for (int c = 0; c < 2; ++c) {
    int ng = (ntile << 7) + (c << 6) + srow;  // global n; tile never spans images
    int b = ng >> 12, yx = ng & 4095;
    int y = yx >> 6, xx = yx & 63;
    boff[c] = ((long)(b * 66 + y) * 66 + xx) * 128 + sch8;
  }

  short* Adst0 = &Alds[(w << 4) * 32];
  short* Adst1 = Adst0 + 64 * 32;
  short* Bdst0 = &Blds[(w << 4) * 32];
  short* Bdst1 = Bdst0 + 64 * 32;

  f32x4 acc[4][4];
#pragma unroll
  for (int i = 0; i < 4; ++i)
#pragma unroll
    for (int j = 0; j < 4; ++j) acc[i][j] = (f32x4)0.f;

  const int wm = (w >> 1) << 6;  // wave's 64-row offset in tile
  const int wn = (w & 1) << 6;   // wave's 64-col offset in tile

#pragma unroll
  for (int khkw = 0; khkw < 9; ++khkw) {
    const int kh = khkw / 3, kw = khkw % 3;
    const long sB = (long)(kh * 66 + kw) * 128;  // uniform shift into x_p
    const int kkb = khkw << 7;
#pragma unroll
    for (int s = 0; s < 2; ++s) {
      // stage BK=64: two 32-k chunks, one barrier pair
#pragma unroll
      for (int c = 0; c < 2; ++c) {
        const int cin0 = (s << 6) + (c << 5);
        const int kk0  = kkb + cin0;
        const int co   = c * 4096;  // chunk offset in shorts
        gload16(wt + aoff0 + kk0, Adst0 + co);
        gload16(wt + aoff1 + kk0, Adst1 + co);
        gload16(xp + boff[0] + sB + cin0, Bdst0 + co);
        gload16(xp + boff[1] + sB + cin0, Bdst1 + co);
      }
      __syncthreads();  // drains vmcnt -> staged data visible
#pragma unroll
      for (int c = 0; c < 2; ++c) {
        const int co = c * 4096;
        short8 af[4], bf[4];
#pragma unroll
        for (int i = 0; i < 4; ++i) {
          int rA = wm + (i << 4) + l15;
          af[i] = *(const short8*)&Alds[co + rA * 32 + ((q ^ ((rA >> 1) & 3)) << 3)];
        }
#pragma unroll
        for (int j = 0; j < 4; ++j) {
          int rB = wn + (j << 4) + l15;
          bf[j] = *(const short8*)&Blds[co + rB * 32 + ((q ^ ((rB >> 1) & 3)) << 3)];
        }
#pragma unroll
        for (int i = 0; i < 4; ++i)
#pragma unroll
          for (int j = 0; j < 4; ++j)
            acc[i][j] = __builtin_amdgcn_mfma_f32_16x16x32_bf16(af[i], bf[j],
                                                                acc[i][j], 0, 0, 0);
      }
      __syncthreads();  // protect LDS before next stage overwrites
    }
  }

  // epilogue: C/D layout col=lane&15, row=quad*4+reg (m89/m91-verified)
  const int ngb = (ntile << 7) + wn;
  const int b   = ngb >> 12;
  const int yxb = ngb & 4095;
  float* outb = out + (long)b * (256 * 4096) + yxb + l15;
#pragma unroll
  for (int i = 0; i < 4; ++i) {
#pragma unroll
    for (int r = 0; r < 4; ++r) {
      const int cout = m0 + wm + (i << 4) + q * 4 + r;
      float* orow = outb + (long)cout * 4096;
#pragma unroll
      for (int j = 0; j < 4; ++j) orow[j * 16] = acc[i][j][r];
    }
  }
}

// Correctness fallback if workspace is too small (slow, fp32 direct conv).
__global__ __launch_bounds__(256) void naive_conv(const float* __restrict__ x,
                                                  const float* __restrict__ wgt,
                                                  float* __restrict__ out) {
  long o = (long)blockIdx.x * 256 + threadIdx.x;
  int xx = (int)(o & 63);
  int y  = (int)((o >> 6) & 63);
  int co = (int)((o >> 12) & 255);
  int b  = (int)(o >> 20);
  float s = 0.f;
  for (int ci = 0; ci < 128; ++ci) {
    for (int kh = 0; kh < 3; ++kh) {
      int iy = y + kh - 1;
      if (iy < 0 || iy > 63) continue;
      for (int kw = 0; kw < 3; ++kw) {
        int ix = xx + kw - 1;
        if (ix < 0 || ix > 63) continue;
        s += x[((long)(b * 128 + ci) * 64 + iy) * 64 + ix] *
             wgt[((co * 128 + ci) * 3 + kh) * 3 + kw];
      }
    }
  }
  out[o] = s;
}

extern "C" void kernel_launch(void* const* d_in, const int* in_sizes, int n_in,
                              void* d_out, int out_size, void* d_ws, size_t ws_size,
                              hipStream_t stream) {
  (void)in_sizes; (void)n_in;
  const float* x   = (const float*)d_in[0];
  const float* wgt = (const float*)d_in[1];
  float* out = (float*)d_out;
  if (ws_size >= WS_NEED) {
    short* xp = (short*)d_ws;
    short* wt = xp + XP_ELEMS;
    prepass_x<<<dim3(64, 32), dim3(256), 0, stream>>>(x, xp);
    prepass_w<<<dim3(WT_ELEMS / 256), dim3(256), 0, stream>>>(wgt, wt);
    conv_gemm<<<dim3(1024, 2), dim3(256), 0, stream>>>(xp, wt, out);
  } else {
    naive_conv<<<dim3(out_size / 256), dim3(256), 0, stream>>>(x, wgt, out);
  }
}